// Round 6
// baseline (228.747 us; speedup 1.0000x reference)
//
#include <hip/hip_runtime.h>

// ScRRAMBLe capsule layer, R6: register-accumulating, software-pipelined
// streaming transform.
//
// R2-R5 post-mortem: four structurally different Wi readers all cap at
// ~2.2 TB/s. Common flaw: per-iteration shfl/atomic tails let the compiler
// collapse to ~1-4 outstanding wave-loads; at ~2000 cyc loaded latency that
// IS 2 TB/s. R6 hot loop is loads+FMA only: 8 scalar accs/lane, two 8 KB
// load groups in flight (16 KB/wave x 16 waves/CU = 256 KB/CU outstanding),
// cross-lane reduce deferred to epilogue (once per 32 KB).

typedef float f4 __attribute__((ext_vector_type(4)));

#define NCH 8   // ij chunks for routing kernel

// ---------------- Kernel A: routing einsum ---------------------------------
// grid (128 i-quads, NCH); block 256. Partials -> ws[0 .. 4MB).
__global__ __launch_bounds__(256) void route_kernel(
    const float* __restrict__ x,
    const float* __restrict__ Ci,
    float* __restrict__ xr_part)
{
    const int iq  = blockIdx.x;
    const int c   = blockIdx.y;
    const int t   = threadIdx.x;
    const int il  = t >> 6;
    const int g   = (t >> 4) & 3;
    const int mq4 = t & 15;
    const int i   = (iq << 2) + il;

    const f4* __restrict__ Ci4 = (const f4*)Ci;
    const f4* __restrict__ x4  = (const f4*)x;

    __shared__ f4 part[1024];

    f4 a0 = {0.f,0.f,0.f,0.f};
    f4 a1 = {0.f,0.f,0.f,0.f};
    f4 a2 = {0.f,0.f,0.f,0.f};
    f4 a3 = {0.f,0.f,0.f,0.f};

    const int ijpc = 2048 / NCH;      // 256
    const int sub  = ijpc >> 2;       // 64 per g-subgroup
    const int base = c * ijpc + g * sub;
    #pragma unroll 4
    for (int it = 0; it < sub; ++it) {
        const int ij = base + it;
        const f4 c4 = Ci4[ij * 512 + i];      // Ci[ij, i, 0:4]
        const f4 xv = x4[(ij << 4) + mq4];    // x[ij, 4*mq4 .. +3]
        a0 += c4.x * xv;
        a1 += c4.y * xv;
        a2 += c4.z * xv;
        a3 += c4.w * xv;
    }

    const int pb = ((g << 2) + il) << 2;
    part[(pb + 0) * 16 + mq4] = a0;
    part[(pb + 1) * 16 + mq4] = a1;
    part[(pb + 2) * 16 + mq4] = a2;
    part[(pb + 3) * 16 + mq4] = a3;
    __syncthreads();

    const int il2 = t >> 6;
    const int r   = (t >> 4) & 3;
    const int mm  = t & 15;
    f4 s = {0.f,0.f,0.f,0.f};
    #pragma unroll
    for (int gg = 0; gg < 4; ++gg)
        s += part[(((gg << 2) + il2) * 4 + r) * 16 + mm];

    f4* __restrict__ xp4 = (f4*)xr_part;
    xp4[(c * 512 + (iq << 2) + il2) * 64 + r * 16 + mm] = s;
}

// ---------------- Kernel A2: reduce chunk partials -> final xr -------------
__global__ __launch_bounds__(256) void reduce_xr_kernel(
    const float* __restrict__ xr_part,
    float* __restrict__ xr)
{
    const int t = blockIdx.x * 256 + threadIdx.x;   // f4 idx
    const f4* __restrict__ p4 = (const f4*)xr_part;
    f4 s = {0.f,0.f,0.f,0.f};
    #pragma unroll
    for (int c = 0; c < NCH; ++c) s += p4[c * 32768 + t];
    ((f4*)xr)[t] = s;
}

// ---------------- Kernel B: pipelined streaming transform ------------------
// 1024 blocks x 256; wave wid = 0..4095 owns half-slice (b = wid>>1, rows
// l in [h*32, h*32+32) of Wi[b]). Hot loop: loads + scalar FMA only.
// Wi f4 index: ((b*4 + k)*64 + l)*16 + m16;  per wave-instr: 1 KB contiguous.
__global__ __launch_bounds__(256) void transform_stream(
    const float* __restrict__ Wi,
    const float* __restrict__ xr,
    float* __restrict__ y)
{
    const int wid  = blockIdx.x * 4 + (threadIdx.x >> 6);
    const int b    = wid >> 1;
    const int h    = wid & 1;
    const int lane = threadIdx.x & 63;
    const int lq   = lane >> 4;
    const int m16  = lane & 15;
    const int i    = b >> 2;

    const f4* __restrict__ W4 = (const f4*)Wi;
    const f4* __restrict__ X4 = (const f4*)xr;

    // xr[i, k, m16 quad] in registers (L2-hot, 64 B/lane)
    const f4 xk0 = X4[i * 64 +  0 + m16];
    const f4 xk1 = X4[i * 64 + 16 + m16];
    const f4 xk2 = X4[i * 64 + 32 + m16];
    const f4 xk3 = X4[i * 64 + 48 + m16];

    // base of k=0 plane for this half-slice; k-plane stride = 1024 f4
    const int base = (b * 256 + h * 32) * 16 + lane;

    f4 wa[8], wb[8];
    #pragma unroll
    for (int jj = 0; jj < 8; ++jj) wa[jj] = W4[base +    0 + jj * 64];  // k=0
    #pragma unroll
    for (int jj = 0; jj < 8; ++jj) wb[jj] = W4[base + 1024 + jj * 64];  // k=1

    float acc[8];
    #pragma unroll
    for (int jj = 0; jj < 8; ++jj)
        acc[jj] = wa[jj].x*xk0.x + wa[jj].y*xk0.y + wa[jj].z*xk0.z + wa[jj].w*xk0.w;

    #pragma unroll
    for (int jj = 0; jj < 8; ++jj) wa[jj] = W4[base + 2048 + jj * 64];  // k=2

    #pragma unroll
    for (int jj = 0; jj < 8; ++jj)
        acc[jj] += wb[jj].x*xk1.x + wb[jj].y*xk1.y + wb[jj].z*xk1.z + wb[jj].w*xk1.w;

    #pragma unroll
    for (int jj = 0; jj < 8; ++jj) wb[jj] = W4[base + 3072 + jj * 64];  // k=3

    #pragma unroll
    for (int jj = 0; jj < 8; ++jj)
        acc[jj] += wa[jj].x*xk2.x + wa[jj].y*xk2.y + wa[jj].z*xk2.z + wa[jj].w*xk2.w;

    #pragma unroll
    for (int jj = 0; jj < 8; ++jj)
        acc[jj] += wb[jj].x*xk3.x + wb[jj].y*xk3.y + wb[jj].z*xk3.z + wb[jj].w*xk3.w;

    // epilogue: reduce over the 16 m-lanes, store (each y elem written once)
    #pragma unroll
    for (int jj = 0; jj < 8; ++jj) {
        float p = acc[jj];
        p += __shfl_xor(p, 1);
        p += __shfl_xor(p, 2);
        p += __shfl_xor(p, 4);
        p += __shfl_xor(p, 8);
        if (m16 == 0) y[b * 64 + h * 32 + jj * 4 + lq] = p;
    }
}

extern "C" void kernel_launch(void* const* d_in, const int* in_sizes, int n_in,
                              void* d_out, int out_size, void* d_ws, size_t ws_size,
                              hipStream_t stream) {
    const float* x  = (const float*)d_in[0];   // 131072
    const float* Ci = (const float*)d_in[1];   // 512*4*512*4
    const float* Wi = (const float*)d_in[2];   // 512*4*4*64*64
    float* y       = (float*)d_out;            // 512*4*64
    float* xr_part = (float*)d_ws;                         // NCH*512*256 f = 4 MiB
    float* xr      = (float*)d_ws + NCH * 512 * 256;       // 512*256 f = 512 KiB

    route_kernel<<<dim3(128, NCH), 256, 0, stream>>>(x, Ci, xr_part);
    reduce_xr_kernel<<<128, 256, 0, stream>>>(xr_part, xr);
    transform_stream<<<1024, 256, 0, stream>>>(Wi, xr, y);
}